// Round 9
// baseline (73.442 us; speedup 1.0000x reference)
//
#include <hip/hip_runtime.h>

typedef float f32x4 __attribute__((ext_vector_type(4)));

constexpr int BLOCK = 256;
constexpr int QPT   = 8;              // queries per thread
constexpr int QPB   = BLOCK * QPT;    // 2048 queries per block

// ---- scalar-pipe point loads (wave-uniform) --------------------------------
// 4 points (64B) per group via s_load_dwordx4 into SGPR quads. SMEM returns
// out of order, so only lgkmcnt(0) drains are used; the 2-buffer ping-pong
// guarantees the only outstanding load at each drain is one compute-block
// old (latency hidden). "+s" ties on the wait order consumers after it.
#define SLOAD(A0, A1, A2, A3, ADDR)                                        \
    asm volatile("s_load_dwordx4 %0, %4, 0\n\t"                            \
                 "s_load_dwordx4 %1, %4, 16\n\t"                           \
                 "s_load_dwordx4 %2, %4, 32\n\t"                           \
                 "s_load_dwordx4 %3, %4, 48"                               \
                 : "=&s"(A0), "=&s"(A1), "=&s"(A2), "=&s"(A3)              \
                 : "s"(ADDR))

#define SWAIT4(A0, A1, A2, A3)                                             \
    asm volatile("s_waitcnt lgkmcnt(0)"                                    \
                 : "+s"(A0), "+s"(A1), "+s"(A2), "+s"(A3))

#define SWAIT8(A0, A1, A2, A3, B0, B1, B2, B3)                             \
    asm volatile("s_waitcnt lgkmcnt(0)"                                    \
                 : "+s"(A0), "+s"(A1), "+s"(A2), "+s"(A3),                 \
                   "+s"(B0), "+s"(B1), "+s"(B2), "+s"(B3))

// t = |p|^2 - 2 q.p  per (query, point); each fma reads exactly ONE sgpr
// operand (the point component); |p|^2 broadcast to VGPR once per point.
#define COMPUTE(A0, A1, A2, A3)                                            \
    do {                                                                   \
        float w0 = A0.w, w1 = A1.w, w2 = A2.w, w3 = A3.w;                  \
        _Pragma("unroll")                                                  \
        for (int k = 0; k < QPT; ++k) {                                    \
            float t0 = fmaf(qx[k], A0.x, w0);                              \
            t0 = fmaf(qy[k], A0.y, t0);                                    \
            t0 = fmaf(qz[k], A0.z, t0);                                    \
            float t1 = fmaf(qx[k], A1.x, w1);                              \
            t1 = fmaf(qy[k], A1.y, t1);                                    \
            t1 = fmaf(qz[k], A1.z, t1);                                    \
            mn[k] = fminf(fminf(t0, t1), mn[k]);                           \
            float t2 = fmaf(qx[k], A2.x, w2);                              \
            t2 = fmaf(qy[k], A2.y, t2);                                    \
            t2 = fmaf(qz[k], A2.z, t2);                                    \
            float t3 = fmaf(qx[k], A3.x, w3);                              \
            t3 = fmaf(qy[k], A3.y, t3);                                    \
            t3 = fmaf(qz[k], A3.z, t3);                                    \
            mn[k] = fminf(fminf(t2, t3), mn[k]);                           \
        }                                                                  \
    } while (0)

// Prep: transform both point sets to (-2x,-2y,-2z,|p|^2) float4 in d_ws.
__global__ __launch_bounds__(256)
void chamfer_prep(const float* __restrict__ rec, const float* __restrict__ data,
                  f32x4* __restrict__ tprec, f32x4* __restrict__ tpdata,
                  int N, int M, int B)
{
    const int i = blockIdx.x * 256 + threadIdx.x;
    const int tot0 = B * N;
    const int tot = B * (N + M);
    if (i >= tot) return;
    const bool isData = i >= tot0;
    const int j = isData ? i - tot0 : i;
    const float* p = (isData ? data : rec) + (size_t)j * 3;
    const float x = p[0], y = p[1], z = p[2];
    f32x4 v = { -2.f * x, -2.f * y, -2.f * z,
                fmaf(x, x, fmaf(y, y, z * z)) };
    (isData ? tpdata : tprec)[j] = v;
}

// Stage 1: partial per-query min over one point-slice. Points arrive via
// the SCALAR pipe (s_load -> SGPR operands); the vector pipes run nothing
// but fma/min3. No LDS at all.
__global__ __launch_bounds__(BLOCK, 8)
void chamfer_partial_kernel(const float* __restrict__ rec,
                            const float* __restrict__ data,
                            const f32x4* __restrict__ tprec,
                            const f32x4* __restrict__ tpdata,
                            float* __restrict__ partial,   // [S][TOTQ]
                            int N, int M, int B, int S)
{
    const int bid = blockIdx.x;
    const int qb  = bid / S;           // query-block index
    const int s   = bid % S;           // point-slice index
    const int q0  = qb * QPB;
    const int TOTQ0 = B * N;
    const int TOTQ  = B * (N + M);

    const bool dir1 = q0 >= TOTQ0;
    const int  lq0  = dir1 ? q0 - TOTQ0 : q0;
    const int  Nq   = dir1 ? M : N;
    const int  Np   = dir1 ? N : M;
    const int  b    = lq0 / Nq;

    const float* __restrict__ qbase =
        (dir1 ? data : rec) + ((size_t)b * Nq + (lq0 % Nq)) * 3;
    const f32x4* __restrict__ tp =
        dir1 ? (tprec + (size_t)b * N) : (tpdata + (size_t)b * M);

    const int slice = Np / S;
    const int p0    = s * slice;

    float qx[QPT], qy[QPT], qz[QPT], mn[QPT];
    #pragma unroll
    for (int k = 0; k < QPT; ++k) {
        const float* qp = qbase + (size_t)(k * BLOCK + threadIdx.x) * 3;
        qx[k] = qp[0]; qy[k] = qp[1]; qz[k] = qp[2];
        mn[k] = 3.4e38f;
    }

    unsigned long long addr = (unsigned long long)(const void*)(tp + p0);
    f32x4 a0, a1, a2, a3, b0, b1, b2, b3;

    // prologue: fill both buffers, drain once
    SLOAD(a0, a1, a2, a3, addr);
    SLOAD(b0, b1, b2, b3, addr + 64ull);
    SWAIT8(a0, a1, a2, a3, b0, b1, b2, b3);
    addr += 128ull;

    const int ngroups = slice / 4;     // 4 points per group
    for (int g = 0; g < ngroups; g += 2) {
        COMPUTE(a0, a1, a2, a3);
        SWAIT4(b0, b1, b2, b3);            // b landed during compute(a)
        SLOAD(a0, a1, a2, a3, addr);       // refill a (g+2)
        addr += 64ull;
        COMPUTE(b0, b1, b2, b3);
        SWAIT4(a0, a1, a2, a3);            // a landed during compute(b)
        SLOAD(b0, b1, b2, b3, addr);       // refill b (g+3)
        addr += 64ull;
    }
    // drain trailing prefetches before endpgm
    SWAIT8(a0, a1, a2, a3, b0, b1, b2, b3);

    float* out = partial + (size_t)s * TOTQ + q0;
    #pragma unroll
    for (int k = 0; k < QPT; ++k)
        out[k * BLOCK + threadIdx.x] = mn[k];
}

// Stage 2: per query, min across S slices, add |q|^2, clamp, block-sum.
__global__ __launch_bounds__(BLOCK)
void chamfer_reduce_kernel(const float* __restrict__ rec,
                           const float* __restrict__ data,
                           const float* __restrict__ partial,
                           float* __restrict__ block_sums,
                           int N, int M, int B, int S)
{
    __shared__ float wsum[BLOCK / 64];
    const int q = blockIdx.x * BLOCK + threadIdx.x;
    const int TOTQ0 = B * N;
    const int TOTQ  = B * (N + M);

    float m0 = 3.4e38f, m1 = 3.4e38f, m2 = 3.4e38f, m3 = 3.4e38f;
    int s = 0;
    for (; s + 4 <= S; s += 4) {
        m0 = fminf(m0, partial[(size_t)(s + 0) * TOTQ + q]);
        m1 = fminf(m1, partial[(size_t)(s + 1) * TOTQ + q]);
        m2 = fminf(m2, partial[(size_t)(s + 2) * TOTQ + q]);
        m3 = fminf(m3, partial[(size_t)(s + 3) * TOTQ + q]);
    }
    for (; s < S; ++s) m0 = fminf(m0, partial[(size_t)s * TOTQ + q]);
    float mn = fminf(fminf(m0, m1), fminf(m2, m3));

    const bool dir1 = q >= TOTQ0;
    const int  lq   = dir1 ? q - TOTQ0 : q;
    const float* qp = (dir1 ? data : rec) + (size_t)lq * 3;
    const float q2  = fmaf(qp[0], qp[0], fmaf(qp[1], qp[1], qp[2] * qp[2]));
    float d = fmaxf(mn + q2, 0.0f);

    for (int off = 32; off; off >>= 1) d += __shfl_down(d, off);
    if ((threadIdx.x & 63) == 0) wsum[threadIdx.x >> 6] = d;
    __syncthreads();
    if (threadIdx.x == 0) {
        float ssum = 0.f;
        for (int w = 0; w < BLOCK / 64; ++w) ssum += wsum[w];
        block_sums[blockIdx.x] = ssum;
    }
}

// Finalize: mean_b( max(sum_rec/N, sum_data/M) )
__global__ __launch_bounds__(256)
void chamfer_finalize(const float* __restrict__ bs, float* __restrict__ out,
                      int N, int M, int B)
{
    __shared__ float smem[256];
    __shared__ float seg[16];
    const int nb0 = N / BLOCK, nb1 = M / BLOCK;
    const int nblk = B * (nb0 + nb1);
    const int tid = threadIdx.x;
    smem[tid] = (tid < nblk) ? bs[tid] : 0.f;
    __syncthreads();
    if (tid < 2 * B) {
        const int dir = tid / B, b = tid % B;
        const int cnt = dir ? nb1 : nb0;
        const int off = dir ? B * nb0 + b * nb1 : b * nb0;
        float v = 0.f;
        for (int i = 0; i < cnt; ++i) v += smem[off + i];
        seg[tid] = v;
    }
    __syncthreads();
    if (tid == 0) {
        float acc = 0.f;
        for (int b = 0; b < B; ++b)
            acc += fmaxf(seg[b] / (float)N, seg[B + b] / (float)M);
        out[0] = acc / (float)B;
    }
}

extern "C" void kernel_launch(void* const* d_in, const int* in_sizes, int n_in,
                              void* d_out, int out_size, void* d_ws, size_t ws_size,
                              hipStream_t stream)
{
    const float* rec  = (const float*)d_in[0];
    const float* data = (const float*)d_in[1];
    const int B = 4;
    const int N = in_sizes[0] / (B * 3);
    const int M = in_sizes[1] / (B * 3);
    const int TOTQ = B * (N + M);

    // ws layout: tprec[B*N] f32x4 | tpdata[B*M] f32x4 | partial[S][TOTQ] | bsums
    const size_t tpBytes = (size_t)B * (N + M) * sizeof(f32x4);
    const int nblk2 = TOTQ / BLOCK;
    int S = 64;   // grid1 = 32*64 = 2048 blocks = 8 blocks/CU
    while (S > 1 &&
           tpBytes + (size_t)S * TOTQ * sizeof(float) +
               (size_t)nblk2 * sizeof(float) > ws_size)
        S >>= 1;

    f32x4* tprec  = (f32x4*)d_ws;
    f32x4* tpdata = tprec + (size_t)B * N;
    float* partial    = (float*)(tpdata + (size_t)B * M);
    float* block_sums = partial + (size_t)S * TOTQ;

    const int prepGrid = (B * (N + M) + 255) / 256;
    chamfer_prep<<<prepGrid, 256, 0, stream>>>(rec, data, tprec, tpdata, N, M, B);

    const int grid1 = (TOTQ / QPB) * S;
    chamfer_partial_kernel<<<grid1, BLOCK, 0, stream>>>(rec, data, tprec, tpdata,
                                                        partial, N, M, B, S);
    chamfer_reduce_kernel<<<nblk2, BLOCK, 0, stream>>>(rec, data, partial,
                                                       block_sums, N, M, B, S);
    chamfer_finalize<<<1, 256, 0, stream>>>(block_sums, (float*)d_out, N, M, B);
}